// Round 15
// baseline (145.533 us; speedup 1.0000x reference)
//
#include <hip/hip_runtime.h>
#include <math.h>

#define T_SEQ 2048
#define D_MODEL 1024
#define NH 16
#define HD 64

typedef unsigned short ushort_t;
typedef unsigned int uint_t;
typedef short short8 __attribute__((ext_vector_type(8)));
typedef float floatx4 __attribute__((ext_vector_type(4)));

// ---- bf16 helpers (RNE) ----
__device__ __forceinline__ ushort_t f2bf(float f) {
    uint_t u = __float_as_uint(f);
    u += 0x7FFFu + ((u >> 16) & 1u);
    return (ushort_t)(u >> 16);
}
__device__ __forceinline__ uint_t pack2(float a, float b) {
    return (uint_t)f2bf(a) | ((uint_t)f2bf(b) << 16);
}
// async global -> LDS, 16B per lane (wave-uniform LDS base + lane*16)
__device__ __forceinline__ void gload16(const ushort_t* g, ushort_t* l) {
    __builtin_amdgcn_global_load_lds(
        (const __attribute__((address_space(1))) void*)g,
        (__attribute__((address_space(3))) void*)l, 16, 0, 0);
}

// ---------------------------------------------------------------------------
// Kernel 0: one-time fp32 -> bf16 convert of x, Wq, Wk, Wv, Wp.
// ---------------------------------------------------------------------------
__global__ __launch_bounds__(256) void to_bf16(
        const float* __restrict__ x,  const float* __restrict__ wq,
        const float* __restrict__ wk, const float* __restrict__ wv,
        const float* __restrict__ wp,
        ushort_t* __restrict__ xb,  ushort_t* __restrict__ wqb,
        ushort_t* __restrict__ wkb, ushort_t* __restrict__ wvb,
        ushort_t* __restrict__ wpb)
{
    size_t i = (size_t)blockIdx.x * 256 + threadIdx.x;
    const float* src; ushort_t* dst; size_t off;
    if (i < 262144)      { src = x;  dst = xb;  off = i; }
    else if (i < 393216) { src = wq; dst = wqb; off = i - 262144; }
    else if (i < 524288) { src = wk; dst = wkb; off = i - 393216; }
    else if (i < 655360) { src = wv; dst = wvb; off = i - 524288; }
    else                 { src = wp; dst = wpb; off = i - 655360; }
    float4 f0 = ((const float4*)src)[off * 2];
    float4 f1 = ((const float4*)src)[off * 2 + 1];
    uint4 u;
    u.x = pack2(f0.x, f0.y); u.y = pack2(f0.z, f0.w);
    u.z = pack2(f1.x, f1.y); u.w = pack2(f1.z, f1.w);
    ((uint4*)dst)[off] = u;
}

// ---------------------------------------------------------------------------
// Kernel 1: QKV GEMM (UNCHANGED). BM=64 BN=128 BK=64, grid (8,32,3) = 768
// = 3/CU, XCD-aware swizzle, 2-phase dbuf, ds-read-first, ONE barrier/iter,
// XOR-swizzle staging. FUSED RMSNorm+RoPE / V blend.
// ---------------------------------------------------------------------------
__global__ __launch_bounds__(256) void gemm_qkv(
        const ushort_t* __restrict__ xb,
        const ushort_t* __restrict__ Wqb, const ushort_t* __restrict__ Wkb,
        const ushort_t* __restrict__ Wvb,
        const float* __restrict__ vi, const float* __restrict__ lam,
        ushort_t* __restrict__ qb, ushort_t* __restrict__ kb,
        ushort_t* __restrict__ vbt)
{
    const int z = blockIdx.z;
    const ushort_t* __restrict__ W = (z == 0) ? Wqb : (z == 1) ? Wkb : Wvb;
    const int d  = blockIdx.y * 8 + blockIdx.x;
    const int ly = (d & 7) * 4 + (d >> 6);
    const int lx = (d >> 3) & 7;
    const int row0 = ly * 64;
    const int col0 = lx * 128;

    __shared__ ushort_t As[2 * 64 * 64];     // 16 KB (2 buffers)
    __shared__ ushort_t Bs[2 * 128 * 64];    // 32 KB

    const int tid = threadIdx.x;
    const int wave = tid >> 6, lane = tid & 63;
    const int wm = wave >> 1, wn = wave & 1;
    const int l15 = lane & 15, quad = lane >> 4;
    const int srow  = tid >> 3;                     // staging row 0..31
    const int sslot = (tid & 7) ^ (srow & 7);       // pre-swizzled 16B slot

    floatx4 acc[2][4];
    #pragma unroll
    for (int i = 0; i < 2; ++i)
        #pragma unroll
        for (int j = 0; j < 4; ++j)
            acc[i][j] = (floatx4){0.f, 0.f, 0.f, 0.f};

    auto stageAB = [&](int k0, int p) {
        ushort_t* Ap = As + p * 4096;
        ushort_t* Bp = Bs + p * 8192;
        #pragma unroll
        for (int c = 0; c < 2; ++c)
            gload16(xb + (size_t)(row0 + c * 32 + srow) * D_MODEL + k0 + sslot * 8,
                    Ap + c * 2048 + tid * 8);
        #pragma unroll
        for (int c = 0; c < 4; ++c)
            gload16(W + (size_t)(col0 + c * 32 + srow) * D_MODEL + k0 + sslot * 8,
                    Bp + c * 2048 + tid * 8);
    };

    stageAB(0, 0);
    int cur = 0;
    for (int k0 = 0; k0 < D_MODEL; k0 += 64) {
        asm volatile("s_waitcnt vmcnt(0)" ::: "memory");
        __builtin_amdgcn_s_barrier();
        const ushort_t* Ac = As + cur * 4096;
        const ushort_t* Bc = Bs + cur * 8192;
        short8 a[2][2], b[2][4];
        #pragma unroll
        for (int kh = 0; kh < 2; ++kh) {
            const int slot = ((kh * 4 + quad) ^ (l15 & 7)) << 3;
            #pragma unroll
            for (int i = 0; i < 2; ++i)
                a[kh][i] = *(const short8*)(Ac + (32 * wm + i * 16 + l15) * 64 + slot);
            #pragma unroll
            for (int j = 0; j < 4; ++j)
                b[kh][j] = *(const short8*)(Bc + (64 * wn + j * 16 + l15) * 64 + slot);
        }
        __builtin_amdgcn_sched_barrier(0);
        if (k0 + 64 < D_MODEL) stageAB(k0 + 64, cur ^ 1);
        __builtin_amdgcn_sched_barrier(0);
        #pragma unroll
        for (int kh = 0; kh < 2; ++kh)
            #pragma unroll
            for (int i = 0; i < 2; ++i)
                #pragma unroll
                for (int j = 0; j < 4; ++j)
                    acc[i][j] = __builtin_amdgcn_mfma_f32_16x16x32_bf16(a[kh][i], b[kh][j], acc[i][j], 0, 0, 0);
        cur ^= 1;
    }

    if (z < 2) {
        ushort_t* __restrict__ o = (z == 0) ? qb : kb;
        const float oscale = (z == 0) ? 0.125f : 1.0f;
        const int hbase = col0 + 64 * wn;
        const float eps = 1.1920929e-7f;
        const float fr = exp2f(-10.0f * (float)l15 / 15.0f);
        #pragma unroll
        for (int i = 0; i < 2; ++i)
            #pragma unroll
            for (int r = 0; r < 4; ++r) {
                const int t = row0 + 32 * wm + i * 16 + quad * 4 + r;
                float v0 = acc[i][0][r], v1 = acc[i][1][r];
                float v2 = acc[i][2][r], v3 = acc[i][3][r];
                float ss = v0 * v0 + v1 * v1 + v2 * v2 + v3 * v3;
                ss += __shfl_xor(ss, 1);
                ss += __shfl_xor(ss, 2);
                ss += __shfl_xor(ss, 4);
                ss += __shfl_xor(ss, 8);
                const float sc = rsqrtf(ss * (1.0f / 64.0f) + eps);
                v0 *= sc; v1 *= sc; v2 *= sc; v3 *= sc;
                const float th = (float)t * fr;
                const float cs = cosf(th), sn = sinf(th);
                const float y0 = v0 * cs + v2 * sn;
                const float y2 = v2 * cs - v0 * sn;
                const size_t rb = (size_t)t * D_MODEL + hbase;
                o[rb +  0 + l15] = f2bf(y0 * oscale);
                o[rb + 16 + l15] = f2bf(v1 * oscale);
                o[rb + 32 + l15] = f2bf(y2 * oscale);
                o[rb + 48 + l15] = f2bf(v3 * oscale);
            }
    } else {
        const float l0 = lam[0], l1 = lam[1];
        #pragma unroll
        for (int i = 0; i < 2; ++i)
            #pragma unroll
            for (int j = 0; j < 4; ++j) {
                const int tb = row0 + 32 * wm + i * 16 + quad * 4;
                const int jj = col0 + 64 * wn + j * 16 + l15;
                float b0 = l0 * acc[i][j][0] + l1 * vi[(size_t)(tb + 0) * D_MODEL + jj];
                float b1 = l0 * acc[i][j][1] + l1 * vi[(size_t)(tb + 1) * D_MODEL + jj];
                float b2 = l0 * acc[i][j][2] + l1 * vi[(size_t)(tb + 2) * D_MODEL + jj];
                float b3 = l0 * acc[i][j][3] + l1 * vi[(size_t)(tb + 3) * D_MODEL + jj];
                uint2 u;
                u.x = pack2(b0, b1);
                u.y = pack2(b2, b3);
                *(uint2*)(vbt + (size_t)jj * T_SEQ + tb) = u;   // [d][t]
            }
    }
}

// ---------------------------------------------------------------------------
// Kernel 2: MFMA flash attention, QBLK=128. FIX vs R14: Q-staging now copies
// the FULL 16 KB tile (each thread 64 B = 32 ushorts = cols c4..c4+31 via
// 4 swizzled uint4 stores; R14 only covered half the columns -> absmax 2.6).
// Each staged K/V tile serves 128 Q-rows -> tile-iterations 8448 -> 4352.
// 4 waves x 32 rows (2 row-frags); 32 MFMA/tile. LDS 48 KB -> 3 blocks/CU.
// Work split per head (grid (16 h, 25 x), big-first):
//   x in [ 0,18): 2-way chunks of Q = 15 - x/2 (chunk 1 holds diag tiles)
//   x in [18,25): direct Q = 24 - x
// Mask when kt >= 2Q. Partials: 288 x 32 KB in dead-ws; Lpart in d_out.
// ---------------------------------------------------------------------------
__global__ __launch_bounds__(256, 3) void attn(
        const ushort_t* __restrict__ qb, const ushort_t* __restrict__ kb,
        const ushort_t* __restrict__ vbt, ushort_t* __restrict__ yb,
        float* __restrict__ Opart, float* __restrict__ Lpart)
{
    const int h = blockIdx.x;
    const int x = blockIdx.y;
    int Q, ct_begin, ct_end, pidx;
    if (x < 18) {                       // 2-way, Q = 15..7
        Q = 15 - (x >> 1);
        const int w = 2 * Q + 2;
        const int mid = Q + 1;
        if ((x & 1) == 0) { ct_begin = 0;   ct_end = mid; }
        else              { ct_begin = mid; ct_end = w;   }   // contains diag
        pidx = h * 18 + x;
    } else {                            // direct, Q = 6..0
        Q = 24 - x;
        ct_begin = 0; ct_end = 2 * Q + 2;
        pidx = -1;
    }
    const int t0 = Q * 128;

    __shared__ ushort_t Ks[2 * 64 * 64];   // [s_local][d] dbuf, swizzled (16 KB)
    __shared__ ushort_t Vs[2 * 64 * 64];   // [d][s_local] dbuf, swizzled (16 KB)
    __shared__ ushort_t QPs[128 * 64];     // Q (128x64) then P, swizzled (16 KB)

    const int tid = threadIdx.x;
    const int wave = tid >> 6, lane = tid & 63;
    const int l15 = lane & 15, quad = lane >> 4;
    const int srow  = tid >> 3;                   // staging row 0..31
    const int sslot = (tid & 7) ^ (srow & 7);     // pre-swizzled 16B slot
    const int bx = l15 & 7;

    // stage Q (128x64) once, swizzled: slot ^= row&7. 64 B/thread (FIXED).
    {
        const int r4 = tid >> 1, c4 = (tid & 1) * 32;
        const ushort_t* src = qb + (size_t)(t0 + r4) * D_MODEL + h * HD + c4;
        uint4 A = ((const uint4*)src)[0];
        uint4 B = ((const uint4*)src)[1];
        uint4 C = ((const uint4*)src)[2];
        uint4 D = ((const uint4*)src)[3];
        const int rs = r4 & 7;
        const int s0 = c4 >> 3;               // 0 or 4
        *(uint4*)(QPs + r4 * 64 + ((s0 + 0) ^ rs) * 8) = A;
        *(uint4*)(QPs + r4 * 64 + ((s0 + 1) ^ rs) * 8) = B;
        *(uint4*)(QPs + r4 * 64 + ((s0 + 2) ^ rs) * 8) = C;
        *(uint4*)(QPs + r4 * 64 + ((s0 + 3) ^ rs) * 8) = D;
    }
    __syncthreads();
    short8 qf[2][2];
    #pragma unroll
    for (int rf = 0; rf < 2; ++rf) {
        const int row = 32 * wave + rf * 16 + l15;
        qf[rf][0] = *(const short8*)(QPs + row * 64 + ((quad ^ bx) << 3));
        qf[rf][1] = *(const short8*)(QPs + row * 64 + (((quad + 4) ^ bx) << 3));
    }

    auto stageKV = [&](int kt, int p) {
        const int s0 = kt * 64;
        ushort_t* Kp = Ks + p * 4096;
        ushort_t* Vp = Vs + p * 4096;
        gload16(kb  + (size_t)(s0 + srow)      * D_MODEL + h * HD + sslot * 8, Kp + tid * 8);
        gload16(kb  + (size_t)(s0 + 32 + srow) * D_MODEL + h * HD + sslot * 8, Kp + 2048 + tid * 8);
        gload16(vbt + (size_t)(h * HD + srow)      * T_SEQ + s0 + sslot * 8,   Vp + tid * 8);
        gload16(vbt + (size_t)(h * HD + 32 + srow) * T_SEQ + s0 + sslot * 8,   Vp + 2048 + tid * 8);
    };

    float l_acc[2][4];
    floatx4 O[2][4];
    #pragma unroll
    for (int rf = 0; rf < 2; ++rf)
        #pragma unroll
        for (int r = 0; r < 4; ++r) l_acc[rf][r] = 0.0f;
    #pragma unroll
    for (int rf = 0; rf < 2; ++rf)
        #pragma unroll
        for (int d = 0; d < 4; ++d) O[rf][d] = (floatx4){0.f, 0.f, 0.f, 0.f};

    stageKV(ct_begin, 0);
    int cur = 0;
    for (int kt = ct_begin; kt < ct_end; ++kt) {
        asm volatile("s_waitcnt vmcnt(0)" ::: "memory");  // cur's 4 loads done
        __builtin_amdgcn_s_barrier();                     // all waves past kt-1

        if (kt + 1 < ct_end) stageKV(kt + 1, cur ^ 1);    // prefetch, full-body cover
        __builtin_amdgcn_sched_barrier(0);

        const ushort_t* Kc = Ks + cur * 4096;
        const ushort_t* Vc = Vs + cur * 4096;

        floatx4 sa[2][4];
        __builtin_amdgcn_s_setprio(1);
        #pragma unroll
        for (int ct = 0; ct < 4; ++ct) {
            const ushort_t* krow = Kc + (ct * 16 + l15) * 64;
            short8 b0 = *(const short8*)(krow + ((quad ^ bx) << 3));
            short8 b1 = *(const short8*)(krow + (((quad + 4) ^ bx) << 3));
            #pragma unroll
            for (int rf = 0; rf < 2; ++rf) {
                floatx4 t4 = (floatx4){0.f, 0.f, 0.f, 0.f};
                t4 = __builtin_amdgcn_mfma_f32_16x16x32_bf16(qf[rf][0], b0, t4, 0, 0, 0);
                t4 = __builtin_amdgcn_mfma_f32_16x16x32_bf16(qf[rf][1], b1, t4, 0, 0, 0);
                sa[rf][ct] = t4;
            }
        }
        __builtin_amdgcn_s_setprio(0);

        if (kt >= 2 * Q) {   // diagonal band (tiles 2Q, 2Q+1)
            const int sbase = kt * 64 - t0;
            #pragma unroll
            for (int ct = 0; ct < 4; ++ct)
                #pragma unroll
                for (int rf = 0; rf < 2; ++rf)
                    #pragma unroll
                    for (int r = 0; r < 4; ++r) {
                        int rowrel = 32 * wave + rf * 16 + quad * 4 + r;
                        int scol = sbase + ct * 16 + l15;
                        if (scol > rowrel) sa[rf][ct][r] = -1e30f;
                    }
        }
        // fixed-max softmax: p = exp(s - 8), per-lane l accumulation only
        float p[4][2][4];
        #pragma unroll
        for (int ct = 0; ct < 4; ++ct)
            #pragma unroll
            for (int rf = 0; rf < 2; ++rf)
                #pragma unroll
                for (int r = 0; r < 4; ++r) {
                    p[ct][rf][r] = __expf(sa[rf][ct][r] - 8.0f);
                    l_acc[rf][r] += p[ct][rf][r];
                }

        // P -> LDS (wave-private 32-row stripe; swizzled; no barrier needed)
        #pragma unroll
        for (int ct = 0; ct < 4; ++ct)
            #pragma unroll
            for (int rf = 0; rf < 2; ++rf)
                #pragma unroll
                for (int r = 0; r < 4; ++r) {
                    const int row = 32 * wave + rf * 16 + quad * 4 + r;
                    const int ps = (ct * 2 + (l15 >> 3)) ^ (row & 7);
                    QPs[row * 64 + ps * 8 + (l15 & 7)] = f2bf(p[ct][rf][r]);
                }

        short8 pa[2][2];
        #pragma unroll
        for (int rf = 0; rf < 2; ++rf) {
            const int row = 32 * wave + rf * 16 + l15;
            pa[rf][0] = *(const short8*)(QPs + row * 64 + ((quad ^ bx) << 3));
            pa[rf][1] = *(const short8*)(QPs + row * 64 + (((quad + 4) ^ bx) << 3));
        }
        __builtin_amdgcn_s_setprio(1);
        #pragma unroll
        for (int dt = 0; dt < 4; ++dt) {
            const ushort_t* vrow = Vc + (dt * 16 + l15) * 64;
            short8 vb0 = *(const short8*)(vrow + ((quad ^ bx) << 3));
            short8 vb1 = *(const short8*)(vrow + (((quad + 4) ^ bx) << 3));
            #pragma unroll
            for (int rf = 0; rf < 2; ++rf) {
                O[rf][dt] = __builtin_amdgcn_mfma_f32_16x16x32_bf16(pa[rf][0], vb0, O[rf][dt], 0, 0, 0);
                O[rf][dt] = __builtin_amdgcn_mfma_f32_16x16x32_bf16(pa[rf][1], vb1, O[rf][dt], 0, 0, 0);
            }
        }
        __builtin_amdgcn_s_setprio(0);
        cur ^= 1;
    }

    // one-time row-sum reduce across the 16 col-lanes
    float l_run[2][4];
    #pragma unroll
    for (int rf = 0; rf < 2; ++rf)
        #pragma unroll
        for (int r = 0; r < 4; ++r) {
            float s = l_acc[rf][r];
            s += __shfl_xor(s, 1);
            s += __shfl_xor(s, 2);
            s += __shfl_xor(s, 4);
            s += __shfl_xor(s, 8);
            l_run[rf][r] = s;
        }

    if (pidx < 0) {
        // direct: normalize and write bf16
        #pragma unroll
        for (int rf = 0; rf < 2; ++rf)
            #pragma unroll
            for (int r = 0; r < 4; ++r) {
                const float inv_l = 1.0f / l_run[rf][r];
                const int t = t0 + 32 * wave + rf * 16 + quad * 4 + r;
                #pragma unroll
                for (int dt = 0; dt < 4; ++dt)
                    yb[(size_t)t * D_MODEL + h * HD + dt * 16 + l15] = f2bf(O[rf][dt][r] * inv_l);
            }
    } else {
        // partial: unnormalized fp32 O + per-row l (fixed max => no m needed)
        float* __restrict__ Op = Opart + (size_t)pidx * 8192;
        #pragma unroll
        for (int rf = 0; rf < 2; ++rf)
            #pragma unroll
            for (int r = 0; r < 4; ++r) {
                const int row = 32 * wave + rf * 16 + quad * 4 + r;
                #pragma unroll
                for (int dt = 0; dt < 4; ++dt)
                    Op[row * 64 + dt * 16 + l15] = O[rf][dt][r];
                if (l15 == 0) Lpart[(size_t)pidx * 128 + row] = l_run[rf][r];
            }
    }
}

// ---------------------------------------------------------------------------
// Kernel 2b: combine the two KV-chunk partials for Q in [7,16).
// Fixed max on both chunks => combined = (O0 + O1) / (l0 + l1).
// grid = (16 h, 9 Q-7), 256 thr. Thread = (row 0..127, 32-col half).
// ---------------------------------------------------------------------------
__global__ __launch_bounds__(256) void attn_combine(
        const float* __restrict__ Opart, const float* __restrict__ Lpart,
        ushort_t* __restrict__ yb)
{
    const int h = blockIdx.x;
    const int Q = 7 + (int)blockIdx.y;   // 7..15
    const int tid = threadIdx.x;
    const int row = tid >> 1;            // 0..127
    const int cs  = (tid & 1) * 32;      // 0/32
    const int p0 = h * 18 + (15 - Q) * 2;

    const float l0 = Lpart[(size_t)p0 * 128 + row];
    const float l1 = Lpart[((size_t)p0 + 1) * 128 + row];
    const float inv = 1.0f / (l0 + l1);

    const float* O0 = Opart + (size_t)p0 * 8192 + row * 64 + cs;
    const float* O1 = O0 + 8192;

    uint_t u[16];
    #pragma unroll
    for (int g = 0; g < 8; ++g) {
        float4 a = ((const float4*)O0)[g];
        float4 b = ((const float4*)O1)[g];
        u[g * 2 + 0] = pack2((a.x + b.x) * inv, (a.y + b.y) * inv);
        u[g * 2 + 1] = pack2((a.z + b.z) * inv, (a.w + b.w) * inv);
    }
    const int t = Q * 128 + row;
    uint4* dst = (uint4*)(yb + (size_t)t * D_MODEL + h * HD + cs);
    dst[0] = make_uint4(u[0],  u[1],  u[2],  u[3]);
    dst[1] = make_uint4(u[4],  u[5],  u[6],  u[7]);
    dst[2] = make_uint4(u[8],  u[9],  u[10], u[11]);
    dst[3] = make_uint4(u[12], u[13], u[14], u[15]);
}

// ---------------------------------------------------------------------------
// Kernel 3: output projection (UNCHANGED), BM=64 BN=64 BK=64,
// grid (16,32) = 512 = 2/CU, XCD-aware swizzle, ds-read-first 2-phase dbuf.
// ---------------------------------------------------------------------------
__global__ __launch_bounds__(256) void gemm_proj(
        const ushort_t* __restrict__ yb, const ushort_t* __restrict__ Wpb,
        float* __restrict__ out)
{
    const int d  = blockIdx.y * 16 + blockIdx.x;
    const int ly = (d & 7) * 4 + (d >> 7);
    const int lx = (d >> 3) & 15;
    const int row0 = ly * 64;
    const int col0 = lx * 64;

    __shared__ ushort_t As[2 * 64 * 64];   // 16 KB
    __shared__ ushort_t Bs[2 * 64 * 64];   // 16 KB

    const int tid = threadIdx.x;
    const int wave = tid >> 6, lane = tid & 63;
    const int l15 = lane & 15, quad = lane >> 4;
    const int srow  = tid >> 3;
    const int sslot = (tid & 7) ^ (srow & 7);

    floatx4 acc4[4];
    #pragma unroll
    for (int j = 0; j < 4; ++j)
        acc4[j] = (floatx4){0.f, 0.f, 0.f, 0.f};

    auto stageAB = [&](int k0, int p) {
        ushort_t* Ap = As + p * 4096;
        ushort_t* Bp = Bs + p * 4096;
        #pragma unroll
        for (int c = 0; c < 2; ++c)
            gload16(yb + (size_t)(row0 + c * 32 + srow) * D_MODEL + k0 + sslot * 8,
                    Ap + c * 2048 + tid * 8);
        #pragma unroll
        for (int c = 0; c < 2; ++c)
            gload16(Wpb + (size_t)(col0 + c * 32 + srow) * D_MODEL + k0 + sslot * 8,
                    Bp + c * 2048 + tid * 8);
    };

    stageAB(0, 0);
    int cur = 0;
    for (int k0 = 0; k0 < D_MODEL; k0 += 64) {
        asm volatile("s_waitcnt vmcnt(0)" ::: "memory");
        __builtin_amdgcn_s_barrier();
        const ushort_t* Ac = As + cur * 4096;
        const ushort_t* Bc = Bs + cur * 4096;
        short8 a[2], b[2][4];
        #pragma unroll
        for (int kh = 0; kh < 2; ++kh) {
            const int slot = ((kh * 4 + quad) ^ (l15 & 7)) << 3;
            a[kh] = *(const short8*)(Ac + (16 * wave + l15) * 64 + slot);
            #pragma unroll
            for (int j = 0; j < 4; ++j)
                b[kh][j] = *(const short8*)(Bc + (j * 16 + l15) * 64 + slot);
        }
        __builtin_amdgcn_sched_barrier(0);
        if (k0 + 64 < D_MODEL) stageAB(k0 + 64, cur ^ 1);
        __builtin_amdgcn_sched_barrier(0);
        #pragma unroll
        for (int kh = 0; kh < 2; ++kh)
            #pragma unroll
            for (int j = 0; j < 4; ++j)
                acc4[j] = __builtin_amdgcn_mfma_f32_16x16x32_bf16(a[kh], b[kh][j], acc4[j], 0, 0, 0);
        cur ^= 1;
    }

    #pragma unroll
    for (int j = 0; j < 4; ++j) {
        const int t = row0 + 16 * wave + quad * 4;
        const int jj = col0 + j * 16 + l15;
        #pragma unroll
        for (int r = 0; r < 4; ++r)
            out[(size_t)(t + r) * D_MODEL + jj] = acc4[j][r];
    }
}

// ---------------------------------------------------------------------------
extern "C" void kernel_launch(void* const* d_in, const int* in_sizes, int n_in,
                              void* d_out, int out_size, void* d_ws, size_t ws_size,
                              hipStream_t stream) {
    (void)in_sizes; (void)n_in; (void)out_size; (void)ws_size;
    const float* x   = (const float*)d_in[0];
    const float* vi  = (const float*)d_in[1];
    const float* Wq  = (const float*)d_in[2];
    const float* Wk  = (const float*)d_in[3];
    const float* Wv  = (const float*)d_in[4];
    const float* Wp  = (const float*)d_in[5];
    const float* lam = (const float*)d_in[6];

    char* base = (char*)d_ws;                                  // 28 MiB used
    ushort_t* xb  = (ushort_t*)(base);                         // [ 0, 4) MiB (dead after gemm_qkv)
    ushort_t* wqb = (ushort_t*)(base + (size_t)4  * 1048576);  // [ 4, 6)  (dead after gemm_qkv)
    ushort_t* wkb = (ushort_t*)(base + (size_t)6  * 1048576);  // [ 6, 8)  (dead after gemm_qkv)
    ushort_t* wvb = (ushort_t*)(base + (size_t)8  * 1048576);  // [ 8,10)  (dead after gemm_qkv)
    ushort_t* wpb = (ushort_t*)(base + (size_t)10 * 1048576);  // [10,12)  (live until gemm_proj)
    ushort_t* qb  = (ushort_t*)(base + (size_t)12 * 1048576);  // [12,16)
    ushort_t* kb  = (ushort_t*)(base + (size_t)16 * 1048576);  // [16,20)
    ushort_t* vbt = (ushort_t*)(base + (size_t)20 * 1048576);  // [20,24)  [d][t]
    ushort_t* yb  = (ushort_t*)(base + (size_t)24 * 1048576);  // [24,28)
    // attn partials: Opart = 288 slots * 32 KB = 9.4 MB in dead [0,10) region;
    // Lpart = 288 * 128 * 4B = 147 KB in d_out (scratch until gemm_proj).
    float* Opart  = (float*)(base);
    float* Lpart  = (float*)d_out;
    float* out = (float*)d_out;

    to_bf16<<<dim3(786432 / 256), 256, 0, stream>>>(x, Wq, Wk, Wv, Wp, xb, wqb, wkb, wvb, wpb);
    gemm_qkv<<<dim3(8, 32, 3), 256, 0, stream>>>(xb, wqb, wkb, wvb, vi, lam, qb, kb, vbt);
    attn<<<dim3(16, 25), 256, 0, stream>>>(qb, kb, vbt, yb, Opart, Lpart);
    attn_combine<<<dim3(16, 9), 256, 0, stream>>>(Opart, Lpart, yb);
    gemm_proj<<<dim3(16, 32), 256, 0, stream>>>(yb, wpb, out);
}

// Round 16
// 140.899 us; speedup vs baseline: 1.0329x; 1.0329x over previous
//
#include <hip/hip_runtime.h>
#include <math.h>

#define T_SEQ 2048
#define D_MODEL 1024
#define NH 16
#define HD 64

typedef unsigned short ushort_t;
typedef unsigned int uint_t;
typedef short short8 __attribute__((ext_vector_type(8)));
typedef float floatx4 __attribute__((ext_vector_type(4)));

// ---- bf16 helpers (RNE) ----
__device__ __forceinline__ ushort_t f2bf(float f) {
    uint_t u = __float_as_uint(f);
    u += 0x7FFFu + ((u >> 16) & 1u);
    return (ushort_t)(u >> 16);
}
__device__ __forceinline__ uint_t pack2(float a, float b) {
    return (uint_t)f2bf(a) | ((uint_t)f2bf(b) << 16);
}
// async global -> LDS, 16B per lane (wave-uniform LDS base + lane*16)
__device__ __forceinline__ void gload16(const ushort_t* g, ushort_t* l) {
    __builtin_amdgcn_global_load_lds(
        (const __attribute__((address_space(1))) void*)g,
        (__attribute__((address_space(3))) void*)l, 16, 0, 0);
}

// ---------------------------------------------------------------------------
// Kernel 0: one-time fp32 -> bf16 convert of x, Wq, Wk, Wv, Wp.
// ---------------------------------------------------------------------------
__global__ __launch_bounds__(256) void to_bf16(
        const float* __restrict__ x,  const float* __restrict__ wq,
        const float* __restrict__ wk, const float* __restrict__ wv,
        const float* __restrict__ wp,
        ushort_t* __restrict__ xb,  ushort_t* __restrict__ wqb,
        ushort_t* __restrict__ wkb, ushort_t* __restrict__ wvb,
        ushort_t* __restrict__ wpb)
{
    size_t i = (size_t)blockIdx.x * 256 + threadIdx.x;
    const float* src; ushort_t* dst; size_t off;
    if (i < 262144)      { src = x;  dst = xb;  off = i; }
    else if (i < 393216) { src = wq; dst = wqb; off = i - 262144; }
    else if (i < 524288) { src = wk; dst = wkb; off = i - 393216; }
    else if (i < 655360) { src = wv; dst = wvb; off = i - 524288; }
    else                 { src = wp; dst = wpb; off = i - 655360; }
    float4 f0 = ((const float4*)src)[off * 2];
    float4 f1 = ((const float4*)src)[off * 2 + 1];
    uint4 u;
    u.x = pack2(f0.x, f0.y); u.y = pack2(f0.z, f0.w);
    u.z = pack2(f1.x, f1.y); u.w = pack2(f1.z, f1.w);
    ((uint4*)dst)[off] = u;
}

// ---------------------------------------------------------------------------
// Kernel 1: QKV GEMM (bf16 MFMA), BM=64 BN=128 BK=64, grid (8,32,3) = 768
// blocks = 3/CU. 2-phase dbuf, ds-read-first, ONE barrier/iter. XOR-swizzle
// staging. FUSED RMSNorm+RoPE (z<2) / V blend (z=2).  [R11 exact]
// ---------------------------------------------------------------------------
__global__ __launch_bounds__(256) void gemm_qkv(
        const ushort_t* __restrict__ xb,
        const ushort_t* __restrict__ Wqb, const ushort_t* __restrict__ Wkb,
        const ushort_t* __restrict__ Wvb,
        const float* __restrict__ vi, const float* __restrict__ lam,
        ushort_t* __restrict__ qb, ushort_t* __restrict__ kb,
        ushort_t* __restrict__ vbt)
{
    const int z = blockIdx.z;
    const ushort_t* __restrict__ W = (z == 0) ? Wqb : (z == 1) ? Wkb : Wvb;
    const int row0 = blockIdx.y * 64;
    const int col0 = blockIdx.x * 128;

    __shared__ ushort_t As[2 * 64 * 64];     // 16 KB (2 buffers)
    __shared__ ushort_t Bs[2 * 128 * 64];    // 32 KB

    const int tid = threadIdx.x;
    const int wave = tid >> 6, lane = tid & 63;
    const int wm = wave >> 1, wn = wave & 1;
    const int l15 = lane & 15, quad = lane >> 4;
    const int srow  = tid >> 3;                     // staging row 0..31
    const int sslot = (tid & 7) ^ (srow & 7);       // pre-swizzled 16B slot

    floatx4 acc[2][4];
    #pragma unroll
    for (int i = 0; i < 2; ++i)
        #pragma unroll
        for (int j = 0; j < 4; ++j)
            acc[i][j] = (floatx4){0.f, 0.f, 0.f, 0.f};

    // stage tile at k-offset k0 into buffer p (6 gloads/wave)
    auto stageAB = [&](int k0, int p) {
        ushort_t* Ap = As + p * 4096;
        ushort_t* Bp = Bs + p * 8192;
        #pragma unroll
        for (int c = 0; c < 2; ++c)
            gload16(xb + (size_t)(row0 + c * 32 + srow) * D_MODEL + k0 + sslot * 8,
                    Ap + c * 2048 + tid * 8);
        #pragma unroll
        for (int c = 0; c < 4; ++c)
            gload16(W + (size_t)(col0 + c * 32 + srow) * D_MODEL + k0 + sslot * 8,
                    Bp + c * 2048 + tid * 8);
    };

    stageAB(0, 0);
    int cur = 0;
    for (int k0 = 0; k0 < D_MODEL; k0 += 64) {
        asm volatile("s_waitcnt vmcnt(0)" ::: "memory");   // cur's 6 loads (1 iter old)
        __builtin_amdgcn_s_barrier();
        const ushort_t* Ac = As + cur * 4096;
        const ushort_t* Bc = Bs + cur * 8192;
        short8 a[2][2], b[2][4];
        #pragma unroll
        for (int kh = 0; kh < 2; ++kh) {
            const int slot = ((kh * 4 + quad) ^ (l15 & 7)) << 3;  // ushort offs
            #pragma unroll
            for (int i = 0; i < 2; ++i)
                a[kh][i] = *(const short8*)(Ac + (32 * wm + i * 16 + l15) * 64 + slot);
            #pragma unroll
            for (int j = 0; j < 4; ++j)
                b[kh][j] = *(const short8*)(Bc + (64 * wn + j * 16 + l15) * 64 + slot);
        }
        __builtin_amdgcn_sched_barrier(0);    // ds_reads stay above
        if (k0 + 64 < D_MODEL) stageAB(k0 + 64, cur ^ 1);
        __builtin_amdgcn_sched_barrier(0);    // gload issue stays above MFMAs
        #pragma unroll
        for (int kh = 0; kh < 2; ++kh)
            #pragma unroll
            for (int i = 0; i < 2; ++i)
                #pragma unroll
                for (int j = 0; j < 4; ++j)
                    acc[i][j] = __builtin_amdgcn_mfma_f32_16x16x32_bf16(a[kh][i], b[kh][j], acc[i][j], 0, 0, 0);
        cur ^= 1;
    }

    if (z < 2) {
        ushort_t* __restrict__ o = (z == 0) ? qb : kb;
        const float oscale = (z == 0) ? 0.125f : 1.0f;   // fold 1/sqrt(hd) into q
        const int hbase = col0 + 64 * wn;
        const float eps = 1.1920929e-7f;
        const float fr = exp2f(-10.0f * (float)l15 / 15.0f);  // rotating-pair freq
        #pragma unroll
        for (int i = 0; i < 2; ++i)
            #pragma unroll
            for (int r = 0; r < 4; ++r) {
                const int t = row0 + 32 * wm + i * 16 + quad * 4 + r;
                float v0 = acc[i][0][r], v1 = acc[i][1][r];
                float v2 = acc[i][2][r], v3 = acc[i][3][r];
                float ss = v0 * v0 + v1 * v1 + v2 * v2 + v3 * v3;
                ss += __shfl_xor(ss, 1);
                ss += __shfl_xor(ss, 2);
                ss += __shfl_xor(ss, 4);
                ss += __shfl_xor(ss, 8);
                const float sc = rsqrtf(ss * (1.0f / 64.0f) + eps);
                v0 *= sc; v1 *= sc; v2 *= sc; v3 *= sc;
                const float th = (float)t * fr;
                const float cs = cosf(th), sn = sinf(th);
                const float y0 = v0 * cs + v2 * sn;   // shown-source rotary sign
                const float y2 = v2 * cs - v0 * sn;
                const size_t rb = (size_t)t * D_MODEL + hbase;
                o[rb +  0 + l15] = f2bf(y0 * oscale);
                o[rb + 16 + l15] = f2bf(v1 * oscale);
                o[rb + 32 + l15] = f2bf(y2 * oscale);
                o[rb + 48 + l15] = f2bf(v3 * oscale);
            }
    } else {
        const float l0 = lam[0], l1 = lam[1];
        #pragma unroll
        for (int i = 0; i < 2; ++i)
            #pragma unroll
            for (int j = 0; j < 4; ++j) {
                const int tb = row0 + 32 * wm + i * 16 + quad * 4;
                const int jj = col0 + 64 * wn + j * 16 + l15;
                float b0 = l0 * acc[i][j][0] + l1 * vi[(size_t)(tb + 0) * D_MODEL + jj];
                float b1 = l0 * acc[i][j][1] + l1 * vi[(size_t)(tb + 1) * D_MODEL + jj];
                float b2 = l0 * acc[i][j][2] + l1 * vi[(size_t)(tb + 2) * D_MODEL + jj];
                float b3 = l0 * acc[i][j][3] + l1 * vi[(size_t)(tb + 3) * D_MODEL + jj];
                uint2 u;
                u.x = pack2(b0, b1);
                u.y = pack2(b2, b3);
                *(uint2*)(vbt + (size_t)jj * T_SEQ + tb) = u;   // [d][t]
            }
    }
}

// ---------------------------------------------------------------------------
// Kernel 2: MFMA flash attention (R11 exact — measured best). QBLK=64.
// Stage-issue at top of each KV iteration (full-body latency cover);
// QPs [64][64] XOR slot-swizzled; LDS 40 KB = 4 blocks/CU; setprio on MFMA
// clusters; fixed-max softmax (|s|<=8 provable); KV-split makespan 14:
//   x in [ 0,28): 2-way chunks of qt = 27 - x/2      (sizes 8..14)
//   x in [28,40): 3-way chunks of qt = 28 + (x-28)/3 (sizes 9..11)
//   x in [40,54): direct qt = 53 - x                 (sizes 14..1, backfill)
// ---------------------------------------------------------------------------
__global__ __launch_bounds__(256) void attn(
        const ushort_t* __restrict__ qb, const ushort_t* __restrict__ kb,
        const ushort_t* __restrict__ vbt, ushort_t* __restrict__ yb,
        float* __restrict__ Opart, float* __restrict__ Lpart)
{
    const int h = blockIdx.x;
    const int x = blockIdx.y;
    int qt, ct_begin, ct_end, pidx;
    if (x < 28) {                       // 2-way, qt 27..14
        qt = 27 - (x >> 1);
        const int w = qt + 1;
        const int c0 = (w + 1) >> 1;
        if ((x & 1) == 0) { ct_begin = 0;  ct_end = c0; }
        else              { ct_begin = c0; ct_end = w;  }   // contains diag
        pidx = h * 40 + 12 + (qt - 14) * 2 + (x & 1);
    } else if (x < 40) {                // 3-way, qt 28..31
        const int xx = x - 28;
        qt = 28 + xx / 3;
        const int c = xx % 3;
        const int w = qt + 1;
        const int b0 = (w + 2) / 3;
        const int b1 = (2 * w + 2) / 3;
        ct_begin = (c == 0) ? 0  : (c == 1) ? b0 : b1;
        ct_end   = (c == 0) ? b0 : (c == 1) ? b1 : w;
        pidx = h * 40 + (qt - 28) * 3 + c;
    } else {                            // direct, qt 13..0
        qt = 53 - x;
        ct_begin = 0; ct_end = qt + 1;
        pidx = -1;
    }
    const int t0 = qt * 64;

    __shared__ ushort_t Ks[2 * 64 * 64];   // [s_local][d] linear, swizzled (16 KB)
    __shared__ ushort_t Vs[2 * 64 * 64];   // [d][s_local] linear, swizzled (16 KB)
    __shared__ ushort_t QPs[64 * 64];      // Q then P, XOR slot-swizzled (8 KB)

    const int tid = threadIdx.x;
    const int wave = tid >> 6, lane = tid & 63;
    const int l15 = lane & 15, quad = lane >> 4;
    const int srow  = tid >> 3;                   // staging row 0..31
    const int sslot = (tid & 7) ^ (srow & 7);     // pre-swizzled 16B slot
    const int bx = l15 & 7;

    // stage Q (64x64) once, swizzled: slot ^= row&7
    {
        const int r4 = tid >> 2, c4 = (tid & 3) * 16;
        const ushort_t* src = qb + (size_t)(t0 + r4) * D_MODEL + h * HD + c4;
        uint4 A = ((const uint4*)src)[0];
        uint4 B = ((const uint4*)src)[1];
        const int rs = r4 & 7;
        const int s0 = (c4 >> 3) ^ rs;        // c4>>3 is even
        const int s1 = ((c4 >> 3) + 1) ^ rs;
        *(uint4*)(QPs + r4 * 64 + s0 * 8) = A;
        *(uint4*)(QPs + r4 * 64 + s1 * 8) = B;
    }
    __syncthreads();
    short8 qf[2];
    qf[0] = *(const short8*)(QPs + (16 * wave + l15) * 64 + ((quad ^ bx) << 3));
    qf[1] = *(const short8*)(QPs + (16 * wave + l15) * 64 + (((quad + 4) ^ bx) << 3));

    auto stageKV = [&](int kt, int p) {
        const int s0 = kt * 64;
        ushort_t* Kp = Ks + p * 4096;
        ushort_t* Vp = Vs + p * 4096;
        gload16(kb  + (size_t)(s0 + srow)      * D_MODEL + h * HD + sslot * 8, Kp + tid * 8);
        gload16(kb  + (size_t)(s0 + 32 + srow) * D_MODEL + h * HD + sslot * 8, Kp + 2048 + tid * 8);
        gload16(vbt + (size_t)(h * HD + srow)      * T_SEQ + s0 + sslot * 8,   Vp + tid * 8);
        gload16(vbt + (size_t)(h * HD + 32 + srow) * T_SEQ + s0 + sslot * 8,   Vp + 2048 + tid * 8);
    };

    float l_acc[4];
    floatx4 O[4];
    #pragma unroll
    for (int r = 0; r < 4; ++r) l_acc[r] = 0.0f;
    #pragma unroll
    for (int d = 0; d < 4; ++d) O[d] = (floatx4){0.f, 0.f, 0.f, 0.f};

    stageKV(ct_begin, 0);
    int cur = 0;
    for (int kt = ct_begin; kt < ct_end; ++kt) {
        asm volatile("s_waitcnt vmcnt(0)" ::: "memory");  // cur's 4 loads done
        __builtin_amdgcn_s_barrier();                     // all waves past iter kt-1

        // issue next-tile prefetch FIRST: covered by the full iteration body
        if (kt + 1 < ct_end) stageKV(kt + 1, cur ^ 1);    // safe: cur^1 last read
        __builtin_amdgcn_sched_barrier(0);                // at kt-1, fenced above

        const ushort_t* Kc = Ks + cur * 4096;
        const ushort_t* Vc = Vs + cur * 4096;

        floatx4 sa[4];
        __builtin_amdgcn_s_setprio(1);
        #pragma unroll
        for (int ct = 0; ct < 4; ++ct) {
            const ushort_t* krow = Kc + (ct * 16 + l15) * 64;
            short8 b0 = *(const short8*)(krow + ((quad ^ bx) << 3));
            short8 b1 = *(const short8*)(krow + (((quad + 4) ^ bx) << 3));
            floatx4 t4 = (floatx4){0.f, 0.f, 0.f, 0.f};
            t4 = __builtin_amdgcn_mfma_f32_16x16x32_bf16(qf[0], b0, t4, 0, 0, 0);
            t4 = __builtin_amdgcn_mfma_f32_16x16x32_bf16(qf[1], b1, t4, 0, 0, 0);
            sa[ct] = t4;
        }
        __builtin_amdgcn_s_setprio(0);

        if (kt == qt) {   // causal mask on the diagonal tile
            #pragma unroll
            for (int ct = 0; ct < 4; ++ct)
                #pragma unroll
                for (int r = 0; r < 4; ++r) {
                    int trow = 16 * wave + quad * 4 + r;
                    int scol = ct * 16 + l15;
                    if (scol > trow) sa[ct][r] = -1e30f;
                }
        }
        // fixed-max softmax: p = exp(s - 8), per-lane l accumulation only
        float p[4][4];
        #pragma unroll
        for (int ct = 0; ct < 4; ++ct)
            #pragma unroll
            for (int r = 0; r < 4; ++r) {
                p[ct][r] = __expf(sa[ct][r] - 8.0f);
                l_acc[r] += p[ct][r];
            }

        // P -> LDS (wave-private 16-row stripe; swizzled; no barrier needed)
        #pragma unroll
        for (int ct = 0; ct < 4; ++ct)
            #pragma unroll
            for (int r = 0; r < 4; ++r) {
                const int row = 16 * wave + quad * 4 + r;
                const int ps = (ct * 2 + (l15 >> 3)) ^ (row & 7);
                QPs[row * 64 + ps * 8 + (l15 & 7)] = f2bf(p[ct][r]);
            }

        short8 pa0 = *(const short8*)(QPs + (16 * wave + l15) * 64 + ((quad ^ bx) << 3));
        short8 pa1 = *(const short8*)(QPs + (16 * wave + l15) * 64 + (((quad + 4) ^ bx) << 3));
        __builtin_amdgcn_s_setprio(1);
        #pragma unroll
        for (int dt = 0; dt < 4; ++dt) {
            const ushort_t* vrow = Vc + (dt * 16 + l15) * 64;
            short8 vb0 = *(const short8*)(vrow + ((quad ^ bx) << 3));
            short8 vb1 = *(const short8*)(vrow + (((quad + 4) ^ bx) << 3));
            O[dt] = __builtin_amdgcn_mfma_f32_16x16x32_bf16(pa0, vb0, O[dt], 0, 0, 0);
            O[dt] = __builtin_amdgcn_mfma_f32_16x16x32_bf16(pa1, vb1, O[dt], 0, 0, 0);
        }
        __builtin_amdgcn_s_setprio(0);
        cur ^= 1;
    }

    // one-time row-sum reduce across the 16 col-lanes
    float l_run[4];
    #pragma unroll
    for (int r = 0; r < 4; ++r) {
        float s = l_acc[r];
        s += __shfl_xor(s, 1);
        s += __shfl_xor(s, 2);
        s += __shfl_xor(s, 4);
        s += __shfl_xor(s, 8);
        l_run[r] = s;
    }

    if (pidx < 0) {
        // direct: normalize and write bf16
        #pragma unroll
        for (int r = 0; r < 4; ++r) {
            const float inv_l = 1.0f / l_run[r];
            const int t = t0 + 16 * wave + quad * 4 + r;
            #pragma unroll
            for (int dt = 0; dt < 4; ++dt)
                yb[(size_t)t * D_MODEL + h * HD + dt * 16 + l15] = f2bf(O[dt][r] * inv_l);
        }
    } else {
        // partial: unnormalized fp32 O + per-row l (fixed max => no m needed)
        float* __restrict__ Op = Opart + (size_t)pidx * 4096;
        #pragma unroll
        for (int r = 0; r < 4; ++r) {
            const int row = 16 * wave + quad * 4 + r;
            #pragma unroll
            for (int dt = 0; dt < 4; ++dt)
                Op[row * 64 + dt * 16 + l15] = O[dt][r];
            if (l15 == 0) Lpart[(size_t)pidx * 64 + row] = l_run[r];
        }
    }
}

// ---------------------------------------------------------------------------
// Kernel 2b: combine the 2 or 3 KV-chunk partials for qt in [14,32).
// Fixed max on all chunks => combined = (sum O_c) / (sum l_c).
// grid = (16 h, 18 qt-14). Thread = one (row, 16-col segment).
// ---------------------------------------------------------------------------
__global__ __launch_bounds__(256) void attn_combine(
        const float* __restrict__ Opart, const float* __restrict__ Lpart,
        ushort_t* __restrict__ yb)
{
    const int h  = blockIdx.x;
    const int qt = 14 + (int)blockIdx.y;   // 14..31
    const int tid = threadIdx.x;
    const int row  = tid >> 2;           // 0..63
    const int dseg = (tid & 3) * 16;     // 0/16/32/48
    int s0, nc;
    if (qt >= 28) { s0 = (qt - 28) * 3;        nc = 3; }
    else          { s0 = 12 + (qt - 14) * 2;   nc = 2; }
    const int p0 = h * 40 + s0;

    float accv[16];
    #pragma unroll
    for (int e = 0; e < 16; ++e) accv[e] = 0.0f;
    float lsum = 0.0f;
    for (int c = 0; c < nc; ++c) {
        const float* Op = Opart + (size_t)(p0 + c) * 4096 + row * 64 + dseg;
        lsum += Lpart[(size_t)(p0 + c) * 64 + row];
        #pragma unroll
        for (int g = 0; g < 4; ++g) {
            float4 a = ((const float4*)Op)[g];
            accv[g * 4 + 0] += a.x;
            accv[g * 4 + 1] += a.y;
            accv[g * 4 + 2] += a.z;
            accv[g * 4 + 3] += a.w;
        }
    }
    const float inv = 1.0f / lsum;

    uint_t u[8];
    #pragma unroll
    for (int g = 0; g < 4; ++g) {
        u[g * 2 + 0] = pack2(accv[g * 4 + 0] * inv, accv[g * 4 + 1] * inv);
        u[g * 2 + 1] = pack2(accv[g * 4 + 2] * inv, accv[g * 4 + 3] * inv);
    }
    const int t = qt * 64 + row;
    uint4* dst = (uint4*)(yb + (size_t)t * D_MODEL + h * HD + dseg);
    dst[0] = make_uint4(u[0], u[1], u[2], u[3]);
    dst[1] = make_uint4(u[4], u[5], u[6], u[7]);
}

// ---------------------------------------------------------------------------
// Kernel 3: output projection (R11 exact), BM=64 BN=64 BK=64, grid (16,32)
// = 512 blocks = 2/CU. 4 row-stripe waves, acc[4]. ds-read-first 2-phase
// dbuf. fp32 out.
// ---------------------------------------------------------------------------
__global__ __launch_bounds__(256) void gemm_proj(
        const ushort_t* __restrict__ yb, const ushort_t* __restrict__ Wpb,
        float* __restrict__ out)
{
    const int row0 = blockIdx.y * 64;
    const int col0 = blockIdx.x * 64;

    __shared__ ushort_t As[2 * 64 * 64];   // 16 KB
    __shared__ ushort_t Bs[2 * 64 * 64];   // 16 KB

    const int tid = threadIdx.x;
    const int wave = tid >> 6, lane = tid & 63;
    const int l15 = lane & 15, quad = lane >> 4;
    const int srow  = tid >> 3;
    const int sslot = (tid & 7) ^ (srow & 7);

    floatx4 acc4[4];
    #pragma unroll
    for (int j = 0; j < 4; ++j)
        acc4[j] = (floatx4){0.f, 0.f, 0.f, 0.f};

    auto stageAB = [&](int k0, int p) {
        ushort_t* Ap = As + p * 4096;
        ushort_t* Bp = Bs + p * 4096;
        #pragma unroll
        for (int c = 0; c < 2; ++c)
            gload16(yb + (size_t)(row0 + c * 32 + srow) * D_MODEL + k0 + sslot * 8,
                    Ap + c * 2048 + tid * 8);
        #pragma unroll
        for (int c = 0; c < 2; ++c)
            gload16(Wpb + (size_t)(col0 + c * 32 + srow) * D_MODEL + k0 + sslot * 8,
                    Bp + c * 2048 + tid * 8);
    };

    stageAB(0, 0);
    int cur = 0;
    for (int k0 = 0; k0 < D_MODEL; k0 += 64) {
        asm volatile("s_waitcnt vmcnt(0)" ::: "memory");
        __builtin_amdgcn_s_barrier();
        const ushort_t* Ac = As + cur * 4096;
        const ushort_t* Bc = Bs + cur * 4096;
        short8 a[2], b[2][4];
        #pragma unroll
        for (int kh = 0; kh < 2; ++kh) {
            const int slot = ((kh * 4 + quad) ^ (l15 & 7)) << 3;
            a[kh] = *(const short8*)(Ac + (16 * wave + l15) * 64 + slot);
            #pragma unroll
            for (int j = 0; j < 4; ++j)
                b[kh][j] = *(const short8*)(Bc + (j * 16 + l15) * 64 + slot);
        }
        __builtin_amdgcn_sched_barrier(0);
        if (k0 + 64 < D_MODEL) stageAB(k0 + 64, cur ^ 1);
        __builtin_amdgcn_sched_barrier(0);
        #pragma unroll
        for (int kh = 0; kh < 2; ++kh)
            #pragma unroll
            for (int j = 0; j < 4; ++j)
                acc4[j] = __builtin_amdgcn_mfma_f32_16x16x32_bf16(a[kh], b[kh][j], acc4[j], 0, 0, 0);
        cur ^= 1;
    }

    #pragma unroll
    for (int j = 0; j < 4; ++j) {
        const int t = row0 + 16 * wave + quad * 4;
        const int jj = col0 + j * 16 + l15;
        #pragma unroll
        for (int r = 0; r < 4; ++r)
            out[(size_t)(t + r) * D_MODEL + jj] = acc4[j][r];
    }
}

// ---------------------------------------------------------------------------
extern "C" void kernel_launch(void* const* d_in, const int* in_sizes, int n_in,
                              void* d_out, int out_size, void* d_ws, size_t ws_size,
                              hipStream_t stream) {
    (void)in_sizes; (void)n_in; (void)out_size; (void)ws_size;
    const float* x   = (const float*)d_in[0];
    const float* vi  = (const float*)d_in[1];
    const float* Wq  = (const float*)d_in[2];
    const float* Wk  = (const float*)d_in[3];
    const float* Wv  = (const float*)d_in[4];
    const float* Wp  = (const float*)d_in[5];
    const float* lam = (const float*)d_in[6];

    char* base = (char*)d_ws;                                  // 28 MiB used
    ushort_t* xb  = (ushort_t*)(base);                         // [ 0, 4) MiB (dead after gemm_qkv)
    ushort_t* wqb = (ushort_t*)(base + (size_t)4  * 1048576);  // [ 4, 6)  (dead after gemm_qkv)
    ushort_t* wkb = (ushort_t*)(base + (size_t)6  * 1048576);  // [ 6, 8)  (dead after gemm_qkv)
    ushort_t* wvb = (ushort_t*)(base + (size_t)8  * 1048576);  // [ 8,10)  (dead after gemm_qkv)
    ushort_t* wpb = (ushort_t*)(base + (size_t)10 * 1048576);  // [10,12)  (live until gemm_proj)
    ushort_t* qb  = (ushort_t*)(base + (size_t)12 * 1048576);  // [12,16)
    ushort_t* kb  = (ushort_t*)(base + (size_t)16 * 1048576);  // [16,20)
    ushort_t* vbt = (ushort_t*)(base + (size_t)20 * 1048576);  // [20,24)  [d][t]
    ushort_t* yb  = (ushort_t*)(base + (size_t)24 * 1048576);  // [24,28)
    // attn partials: Opart = 640 * 16 KB = 10 MiB in dead [0,10) region;
    // Lpart = 640 * 64 * 4B = 160 KB in d_out (scratch until gemm_proj).
    float* Opart  = (float*)(base);
    float* Lpart  = (float*)d_out;
    float* out = (float*)d_out;

    to_bf16<<<dim3(786432 / 256), 256, 0, stream>>>(x, Wq, Wk, Wv, Wp, xb, wqb, wkb, wvb, wpb);
    gemm_qkv<<<dim3(8, 32, 3), 256, 0, stream>>>(xb, wqb, wkb, wvb, vi, lam, qb, kb, vbt);
    attn<<<dim3(16, 54), 256, 0, stream>>>(qb, kb, vbt, yb, Opart, Lpart);
    attn_combine<<<dim3(16, 18), 256, 0, stream>>>(Opart, Lpart, yb);
    gemm_proj<<<dim3(16, 32), 256, 0, stream>>>(yb, wpb, out);
}